// Round 6
// baseline (659.567 us; speedup 1.0000x reference)
//
#include <hip/hip_runtime.h>

#define V 80000
#define E 640000
#define D 128
#define NREL 500
#define HALF (E/2)
#define NGROUP 1000
#define EP (E + NGROUP * 32)
#define NBLK_D ((V + 1023) / 1024)
#define NREP 160
#define SLAB 4000   // E / NREP

typedef __attribute__((ext_vector_type(8))) short s8v;
typedef __attribute__((ext_vector_type(4))) float f4v;
typedef __attribute__((ext_vector_type(4))) int i4v;

__device__ __forceinline__ unsigned short f2bf(float f) {
  unsigned u = __float_as_uint(f);
  return (unsigned short)((u + 0x7fffu + ((u >> 16) & 1u)) >> 16);
}

__global__ void k_init(float* esum, float* colsum, float* colsumsq,
                       int* dcnt, int* dcnt2, int* hist, int* cnt2rep,
                       float* coef, int* gsrc, int* dposA) {
  int i = blockIdx.x * 256 + threadIdx.x;
  if (i < V) { esum[i] = 0.f; dcnt[i] = 0; dcnt2[i] = 0; }
  if (i < D) { colsum[i] = 0.f; colsumsq[i] = 0.f; }
  if (i < NGROUP * NREP) { hist[i] = 0; cnt2rep[i] = 0; }
  if (i < EP) { coef[i] = 0.f; gsrc[i] = 0; dposA[i] = -1; }
}

// fused prep: blocks [0,500)=rel/out1/rw/relb ; [500,628)=mltb ; [628,884)=wtb
__global__ void k_prep(const float* __restrict__ rel, const float* __restrict__ w_rel,
                       const float* __restrict__ attn_w, const float* __restrict__ loop_rel,
                       const float* __restrict__ loop_w, const float* __restrict__ in_w,
                       const float* __restrict__ out_w, float* __restrict__ out1,
                       float* __restrict__ rw, unsigned short* __restrict__ relb,
                       unsigned short* __restrict__ mltb, unsigned short* __restrict__ wtb) {
  int b = blockIdx.x, n = threadIdx.x;
  if (b < NREL) {
    __shared__ float rs[D];
    __shared__ float red[D];
    float rv = rel[b * D + n];
    rs[n] = rv;
    relb[b * D + n] = f2bf(rv);
    red[n] = rv * attn_w[D + n];
    __syncthreads();
    float acc = 0.f;
    #pragma unroll 8
    for (int j = 0; j < D; ++j) acc += rs[j] * w_rel[j * D + n];
    out1[b * D + n] = acc;
    if (n == 0) {
      float s = 0.f;
      for (int j = 0; j < D; ++j) s += red[j];
      rw[b] = s;
    }
  } else if (b < NREL + D) {
    int j = b - NREL;
    __shared__ float ls[2 * D];
    ls[n] = loop_rel[n]; ls[n + D] = loop_rel[n];
    __syncthreads();
    float acc = 0.f;
    #pragma unroll 8
    for (int k = 0; k < D; ++k) acc += ls[j + k] * loop_w[k * D + n];
    mltb[n * D + j] = f2bf(acc);
  } else {
    int bw = b - NREL - D;
    int h = bw >> 7, n2 = bw & 127;
    const float* W = h ? out_w : in_w;
    wtb[h * 16384 + n2 * D + n] = f2bf(W[n * D + n2]);
  }
}

// fused: x -> bf16 xb ; sxw/dxw projections (reads x once)
__global__ void k_xbproj(const float* __restrict__ x, const float* __restrict__ attn_w,
                         unsigned* __restrict__ xb32, float* __restrict__ sxw,
                         float* __restrict__ dxw) {
  int tid = threadIdx.x;
  int wid = tid >> 6, lane = tid & 63;
  float ws0 = attn_w[2 * lane], ws1 = attn_w[2 * lane + 1];
  float wd0 = attn_w[256 + 2 * lane], wd1 = attn_w[256 + 2 * lane + 1];
  for (int v = blockIdx.x * 4 + wid; v < V; v += 2048 * 4) {
    float2 xv = *(const float2*)&x[(size_t)v * D + 2 * lane];
    float ps = xv.x * ws0 + xv.y * ws1;
    float pd = xv.x * wd0 + xv.y * wd1;
    #pragma unroll
    for (int off = 32; off; off >>= 1) { ps += __shfl_xor(ps, off); pd += __shfl_xor(pd, off); }
    if (lane == 0) { sxw[v] = ps; dxw[v] = pd; }
    xb32[(size_t)v * 64 + lane] = (unsigned)f2bf(xv.x) | ((unsigned)f2bf(xv.y) << 16);
  }
}

// MbT[g][n][j] = sum_k rel_t[(j+k)%128] * W_h[k][n]  via MFMA
__global__ __launch_bounds__(256) void k_mbt2(const unsigned short* __restrict__ relb,
    const unsigned short* __restrict__ wtb, unsigned short* __restrict__ mbt) {
  __shared__ unsigned short relp[256];
  __shared__ unsigned short Wl[D * D];
  int g = blockIdx.x, tid = threadIdx.x;
  int t = (g >= NREL) ? g - NREL : g;
  const unsigned short* wt = wtb + (g >= NREL ? 16384 : 0);
  relp[tid] = relb[t * D + (tid & 127)];
  #pragma unroll
  for (int i = 0; i < 8; ++i) {
    int idx = tid + i * 256;
    int n = idx >> 4, kc = idx & 15;
    *(uint4*)((char*)Wl + n * 256 + ((kc ^ (n & 7)) << 4)) = *(const uint4*)(wt + n * D + kc * 8);
  }
  __syncthreads();
  int wid = tid >> 6, ln = tid & 15, hi = (tid & 63) >> 4;
  s8v af[2][4];
  #pragma unroll
  for (int m = 0; m < 2; ++m) {
    int j = wid * 32 + m * 16 + ln;
    #pragma unroll
    for (int ks = 0; ks < 4; ++ks) {
      int o = j + ks * 32 + hi * 8;
      s8v a;
      #pragma unroll
      for (int i = 0; i < 8; ++i) a[i] = (short)relp[o + i];
      af[m][ks] = a;
    }
  }
  f4v acc[2][8];
  #pragma unroll
  for (int m = 0; m < 2; ++m)
    #pragma unroll
    for (int nn = 0; nn < 8; ++nn) acc[m][nn] = (f4v){0.f, 0.f, 0.f, 0.f};
  #pragma unroll
  for (int ks = 0; ks < 4; ++ks) {
    #pragma unroll
    for (int nn = 0; nn < 8; ++nn) {
      int n2 = nn * 16 + ln;
      int kc = (ks * 4 + hi) ^ (n2 & 7);
      s8v b = *(const s8v*)((const char*)Wl + n2 * 256 + (kc << 4));
      #pragma unroll
      for (int m = 0; m < 2; ++m)
        acc[m][nn] = __builtin_amdgcn_mfma_f32_16x16x32_bf16(af[m][ks], b, acc[m][nn], 0, 0, 0);
    }
  }
  size_t gb = (size_t)g * (D * D);
  #pragma unroll
  for (int m = 0; m < 2; ++m)
    #pragma unroll
    for (int nn = 0; nn < 8; ++nn) {
      int jb = wid * 32 + m * 16 + hi * 4;
      unsigned long long pk = (unsigned long long)f2bf(acc[m][nn][0])
        | ((unsigned long long)f2bf(acc[m][nn][1]) << 16)
        | ((unsigned long long)f2bf(acc[m][nn][2]) << 32)
        | ((unsigned long long)f2bf(acc[m][nn][3]) << 48);
      *(unsigned long long*)&mbt[gb + (size_t)(nn * 16 + ln) * D + jb] = pk;
    }
}

// out0 init = (xb @ MloopT^T)/3 + bias  via MFMA
__global__ __launch_bounds__(256) void k_lgemm(const unsigned short* __restrict__ xb,
    const unsigned short* __restrict__ mltb, const float* __restrict__ bias,
    float* __restrict__ out0) {
  __shared__ unsigned short Wl[D * D];
  int tid = threadIdx.x;
  #pragma unroll
  for (int i = 0; i < 8; ++i) {
    int idx = tid + i * 256;
    int n = idx >> 4, kc = idx & 15;
    *(uint4*)((char*)Wl + n * 256 + ((kc ^ (n & 7)) << 4)) = *(const uint4*)(mltb + n * D + kc * 8);
  }
  __syncthreads();
  int wid = tid >> 6, ln = tid & 15, hi = (tid & 63) >> 4;
  int rbase = blockIdx.x * 128 + wid * 32;
  s8v af[2][4];
  #pragma unroll
  for (int m = 0; m < 2; ++m)
    #pragma unroll
    for (int ks = 0; ks < 4; ++ks)
      af[m][ks] = *(const s8v*)(xb + (size_t)(rbase + m * 16 + ln) * D + ks * 32 + hi * 8);
  f4v acc[2][8];
  #pragma unroll
  for (int m = 0; m < 2; ++m)
    #pragma unroll
    for (int nn = 0; nn < 8; ++nn) acc[m][nn] = (f4v){0.f, 0.f, 0.f, 0.f};
  #pragma unroll
  for (int ks = 0; ks < 4; ++ks) {
    #pragma unroll
    for (int nn = 0; nn < 8; ++nn) {
      int n2 = nn * 16 + ln;
      int kc = (ks * 4 + hi) ^ (n2 & 7);
      s8v b = *(const s8v*)((const char*)Wl + n2 * 256 + (kc << 4));
      #pragma unroll
      for (int m = 0; m < 2; ++m)
        acc[m][nn] = __builtin_amdgcn_mfma_f32_16x16x32_bf16(af[m][ks], b, acc[m][nn], 0, 0, 0);
    }
  }
  float bcol[8];
  #pragma unroll
  for (int nn = 0; nn < 8; ++nn) bcol[nn] = bias[nn * 16 + ln];
  #pragma unroll
  for (int m = 0; m < 2; ++m)
    #pragma unroll
    for (int nn = 0; nn < 8; ++nn)
      #pragma unroll
      for (int r = 0; r < 4; ++r)
        out0[(size_t)(rbase + m * 16 + hi * 4 + r) * D + nn * 16 + ln] =
            acc[m][nn][r] * (1.f / 3.f) + bcol[nn];
}

// fused per-edge phase A
__global__ void k_edge(const int* __restrict__ src, const int* __restrict__ dst,
                       const int* __restrict__ et, const float* __restrict__ sxw,
                       const float* __restrict__ dxw, const float* __restrict__ rw,
                       float* __restrict__ evals, float* __restrict__ esum,
                       int* __restrict__ dcnt, int* __restrict__ hist) {
  int i = blockIdx.x * 256 + threadIdx.x;
  if (i >= E) return;
  int d = dst[i];
  float ev = sxw[src[i]] + rw[et[i]] + dxw[d];
  ev = ev >= 0.f ? ev : 0.01f * ev;
  float xv = __expf(ev);
  evals[i] = xv;
  atomicAdd(&esum[d], xv);
  atomicAdd(&dcnt[d], 1);
  int g = et[i] + ((i >= HALF) ? NREL : 0);
  int r = i / SLAB;
  atomicAdd(&hist[g * NREP + r], 1);
}

// fused: cnt <- rowsum(hist); padded exclusive scan -> poffs; repbase
__global__ void k_meta(const int* __restrict__ hist, int* __restrict__ cnt,
                       int* __restrict__ poffs, int* __restrict__ repbase) {
  __shared__ int tmp[1024];
  int t = threadIdx.x;
  int c = 0;
  if (t < NGROUP) {
    for (int r = 0; r < NREP; ++r) c += hist[t * NREP + r];
    cnt[t] = c;
  }
  int pc = (c + 31) & ~31;
  tmp[t] = pc;
  __syncthreads();
  #pragma unroll
  for (int off = 1; off < 1024; off <<= 1) {
    int v = (t >= off) ? tmp[t - off] : 0;
    __syncthreads();
    tmp[t] += v;
    __syncthreads();
  }
  int po = tmp[t] - pc;
  poffs[t] = po;
  if (t < NGROUP) {
    int running = po;
    for (int r = 0; r < NREP; ++r) {
      repbase[t * NREP + r] = running;
      running += hist[t * NREP + r];
    }
  }
}

__global__ void k_dscan1(const int* __restrict__ dcnt, int* __restrict__ dloc,
                         int* __restrict__ dtot) {
  __shared__ int tmp[1024];
  int t = threadIdx.x, i = blockIdx.x * 1024 + t;
  int v = (i < V) ? dcnt[i] : 0;
  tmp[t] = v;
  __syncthreads();
  #pragma unroll
  for (int off = 1; off < 1024; off <<= 1) {
    int u = (t >= off) ? tmp[t - off] : 0;
    __syncthreads();
    tmp[t] += u;
    __syncthreads();
  }
  if (i < V) dloc[i] = tmp[t] - v;
  if (t == 1023) dtot[blockIdx.x] = tmp[t];
}

__global__ void k_dscan2(const int* __restrict__ dtot, int* __restrict__ dboff) {
  __shared__ int tmp[128];
  int t = threadIdx.x;
  int v = (t < NBLK_D) ? dtot[t] : 0;
  tmp[t] = v;
  __syncthreads();
  #pragma unroll
  for (int off = 1; off < 128; off <<= 1) {
    int u = (t >= off) ? tmp[t - off] : 0;
    __syncthreads();
    tmp[t] += u;
    __syncthreads();
  }
  dboff[t] = tmp[t] - v;
}

__global__ void k_dscan3(const int* __restrict__ dloc, const int* __restrict__ dboff,
                         int* __restrict__ doffs) {
  int i = blockIdx.x * 1024 + threadIdx.x;
  if (i < V) doffs[i] = dloc[i] + dboff[i >> 10];
}

__global__ void k_scatter(const int* __restrict__ src, const int* __restrict__ dst,
                          const int* __restrict__ et, const float* __restrict__ ee,
                          const float* __restrict__ esum, const float* __restrict__ enorm,
                          const int* __restrict__ repbase, int* __restrict__ cnt2rep,
                          const int* __restrict__ doffs, int* __restrict__ dcnt2,
                          int* __restrict__ gsrc, int* __restrict__ dposA,
                          float* __restrict__ coef) {
  int i = blockIdx.x * 256 + threadIdx.x;
  if (i >= E) return;
  int g = et[i] + ((i >= HALF) ? NREL : 0);
  int r = i / SLAB;
  int pos = repbase[g * NREP + r] + atomicAdd(&cnt2rep[g * NREP + r], 1);
  int d = dst[i];
  gsrc[pos] = src[i];
  coef[pos] = ee[i] / esum[d] * enorm[i] * (1.f / 3.f);
  int dr = atomicAdd(&dcnt2[d], 1);
  dposA[pos] = doffs[d] + dr;
}

// grouped gather-GEMM, 16-edge tiles, double-buffered A gather, group split 2 ways
__global__ __launch_bounds__(256, 4) void k_msg3(const unsigned short* __restrict__ xb,
    const unsigned short* __restrict__ mbt, const int* __restrict__ cnt,
    const int* __restrict__ poffs, const int* __restrict__ gsrc,
    const int* __restrict__ dposA, const float* __restrict__ coef,
    const int* __restrict__ doffs, int loNode, int hiNode,
    unsigned short* __restrict__ msgb) {
  __shared__ uint4 Blds4[(D * 272) / 16];
  unsigned char* Bldsb = (unsigned char*)Blds4;
  int g = blockIdx.x >> 1, half = blockIdx.x & 1;
  int c = cnt[g];
  if (c == 0) return;
  int tid = threadIdx.x;
  const uint4* Mg = (const uint4*)(mbt + (size_t)g * (D * D));
  #pragma unroll
  for (int i = 0; i < 8; ++i) {
    int idx = tid + i * 256;
    int row = idx >> 4, col = (idx & 15) * 16;
    Blds4[(row * 272 + col) >> 4] = Mg[idx];
  }
  __syncthreads();
  int b1 = doffs[loNode];
  int b2 = (hiNode >= V) ? E : doffs[hiNode];
  int wid = tid >> 6, ln = tid & 15, hi = (tid & 63) >> 4;
  int base0 = poffs[g];
  int nch = (c + 15) >> 4;
  int ch = half * 4 + wid;
  int sr = (ch < nch) ? gsrc[base0 + ch * 16 + ln] : 0;
  s8v afp[4];
  if (ch < nch) {
    const unsigned short* xr = xb + (size_t)sr * D + hi * 8;
    #pragma unroll
    for (int ks = 0; ks < 4; ++ks) afp[ks] = *(const s8v*)(xr + ks * 32);
  }
  for (; ch < nch; ch += 8) {
    int base = base0 + ch * 16;
    f4v cf = *(const f4v*)&coef[base + hi * 4];
    i4v dp = *(const i4v*)&dposA[base + hi * 4];
    int nc2 = ch + 8;
    int srn = (nc2 < nch) ? gsrc[base0 + nc2 * 16 + ln] : sr;
    s8v afc[4];
    #pragma unroll
    for (int ks = 0; ks < 4; ++ks) afc[ks] = afp[ks];
    f4v acc[8];
    #pragma unroll
    for (int n = 0; n < 8; ++n) acc[n] = (f4v){0.f, 0.f, 0.f, 0.f};
    #pragma unroll
    for (int ks = 0; ks < 4; ++ks) {
      #pragma unroll
      for (int n = 0; n < 8; ++n) {
        int row = n * 16 + ln;
        s8v bf = *(const s8v*)(Bldsb + row * 272 + ks * 64 + hi * 16);
        acc[n] = __builtin_amdgcn_mfma_f32_16x16x32_bf16(afc[ks], bf, acc[n], 0, 0, 0);
      }
    }
    // prefetch next chunk's A rows while softmax runs
    {
      const unsigned short* xr = xb + (size_t)srn * D + hi * 8;
      #pragma unroll
      for (int ks = 0; ks < 4; ++ks) afp[ks] = *(const s8v*)(xr + ks * 32);
    }
    sr = srn;
    f4v mx = acc[0];
    #pragma unroll
    for (int n = 1; n < 8; ++n)
      #pragma unroll
      for (int j = 0; j < 4; ++j) mx[j] = fmaxf(mx[j], acc[n][j]);
    #pragma unroll
    for (int off = 1; off < 16; off <<= 1)
      #pragma unroll
      for (int j = 0; j < 4; ++j) mx[j] = fmaxf(mx[j], __shfl_xor(mx[j], off));
    f4v sum = (f4v){0.f, 0.f, 0.f, 0.f};
    #pragma unroll
    for (int n = 0; n < 8; ++n)
      #pragma unroll
      for (int j = 0; j < 4; ++j) {
        float e = __expf(acc[n][j] - mx[j]);
        acc[n][j] = e;
        sum[j] += e;
      }
    #pragma unroll
    for (int off = 1; off < 16; off <<= 1)
      #pragma unroll
      for (int j = 0; j < 4; ++j) sum[j] += __shfl_xor(sum[j], off);
    #pragma unroll
    for (int j = 0; j < 4; ++j) {
      int dpos = dp[j];
      if (dpos >= b1 && dpos < b2) {
        size_t rowb = (size_t)(dpos - b1) * D;
        float s = cf[j] / sum[j];
        #pragma unroll
        for (int n = 0; n < 8; ++n)
          msgb[rowb + n * 16 + ln] = f2bf(acc[n][j] * s);
      }
    }
  }
}

// per-node segment sum of dst-sorted messages into out0
__global__ void k_sum(const unsigned short* __restrict__ msgb, const int* __restrict__ doffs,
                      const int* __restrict__ dcnt, float* __restrict__ out0,
                      int loNode, int hiNode) {
  int d = loNode + blockIdx.x * 4 + (threadIdx.x >> 6);
  if (d >= hiNode) return;
  int lane = threadIdx.x & 63;
  int b1 = doffs[loNode];
  int start = doffs[d] - b1, len = dcnt[d];
  float a0 = 0.f, a1 = 0.f;
  const unsigned short* mp = msgb + (size_t)start * D + lane * 2;
  for (int r = 0; r < len; ++r) {
    unsigned u = *(const unsigned*)(mp + (size_t)r * D);
    a0 += __uint_as_float(u << 16);
    a1 += __uint_as_float(u & 0xffff0000u);
  }
  float2* o = (float2*)&out0[(size_t)d * D + lane * 2];
  float2 v = *o;
  v.x += a0; v.y += a1;
  *o = v;
}

__global__ void k_bn_stats(const float* __restrict__ out0, float* __restrict__ colsum,
                           float* __restrict__ colsumsq) {
  int tid = threadIdx.x;
  int col = tid & 127;
  int v0 = blockIdx.x * 2 + (tid >> 7);
  float s = 0.f, s2 = 0.f;
  for (int v = v0; v < V; v += 1024) {
    float val = out0[(size_t)v * D + col];
    s += val; s2 += val * val;
  }
  atomicAdd(&colsum[col], s);
  atomicAdd(&colsumsq[col], s2);
}

__global__ void k_bn_norm(float* __restrict__ out0, const float* __restrict__ colsum,
                          const float* __restrict__ colsumsq) {
  int i = blockIdx.x * 256 + threadIdx.x;
  if (i >= V * D) return;
  int c = i & 127;
  float mean = colsum[c] * (1.f / V);
  float var = colsumsq[c] * (1.f / V) - mean * mean;
  out0[i] = (out0[i] - mean) * rsqrtf(var + 1e-5f);
}

extern "C" void kernel_launch(void* const* d_in, const int* in_sizes, int n_in,
                              void* d_out, int out_size, void* d_ws, size_t ws_size,
                              hipStream_t stream) {
  const float* x        = (const float*)d_in[0];
  const float* rel      = (const float*)d_in[4];
  const float* enorm    = (const float*)d_in[5];
  const float* in_w     = (const float*)d_in[6];
  const float* out_w    = (const float*)d_in[7];
  const float* loop_w   = (const float*)d_in[8];
  const float* w_rel    = (const float*)d_in[9];
  const float* loop_rel = (const float*)d_in[10];
  const float* attn_w   = (const float*)d_in[11];
  const float* bias     = (const float*)d_in[12];
  const int* src = (const int*)d_in[13];
  const int* dst = (const int*)d_in[14];
  const int* et  = (const int*)d_in[15];

  float* out0 = (float*)d_out;
  float* out1 = out0 + (size_t)V * D;

  float* base = (float*)d_ws;
  size_t off = 0;
  float* sxw = base + off;      off += V;
  float* dxw = base + off;      off += V;
  float* esum = base + off;     off += V;
  float* evals = base + off;    off += E;
  float* rw = base + off;       off += 512;
  float* colsum = base + off;   off += 128;
  float* colsumsq = base + off; off += 128;
  int* cnt = (int*)(base + off);   off += 1024;
  int* poffs = (int*)(base + off); off += 1024;
  int* hist = (int*)(base + off);     off += NGROUP * NREP;
  int* repbase = (int*)(base + off);  off += NGROUP * NREP;
  int* cnt2rep = (int*)(base + off);  off += NGROUP * NREP;
  int* dcnt = (int*)(base + off);  off += V;
  int* dcnt2 = (int*)(base + off); off += V;
  int* dloc = (int*)(base + off);  off += V;
  int* doffs = (int*)(base + off); off += V;
  int* dtot = (int*)(base + off);  off += 128;
  int* dboff = (int*)(base + off); off += 128;
  float* coef = base + off;        off += EP;
  int* gsrc = (int*)(base + off);  off += EP;
  int* dposA = (int*)(base + off); off += EP;
  unsigned short* mltb = (unsigned short*)(base + off); off += D * D / 2;
  unsigned short* relb = (unsigned short*)(base + off); off += NREL * D / 2;
  unsigned short* wtb  = (unsigned short*)(base + off); off += 2 * D * D / 2;
  unsigned short* xb   = (unsigned short*)(base + off); off += (size_t)V * D / 2;
  unsigned short* mbt  = (unsigned short*)(base + off); off += (size_t)NGROUP * D * D / 2;
  unsigned short* msgb = (unsigned short*)(base + off);

  size_t availF = (ws_size / 4 > off) ? (ws_size / 4 - off) : 0;
  int ns = 1;
  if ((size_t)EP * (D / 2) > availF) {
    ns = 2;
    while (ns < 64 && (size_t)(E / ns + 16384) * (D / 2) > availF) ns *= 2;
  }

  k_init<<<(EP + 255) / 256, 256, 0, stream>>>(esum, colsum, colsumsq, dcnt, dcnt2,
                                               hist, cnt2rep, coef, gsrc, dposA);
  k_prep<<<NREL + D + 256, 128, 0, stream>>>(rel, w_rel, attn_w, loop_rel, loop_w,
                                             in_w, out_w, out1, rw, relb, mltb, wtb);
  k_xbproj<<<2048, 256, 0, stream>>>(x, attn_w, (unsigned*)xb, sxw, dxw);
  k_mbt2<<<NGROUP, 256, 0, stream>>>(relb, wtb, mbt);
  k_lgemm<<<V / 128, 256, 0, stream>>>(xb, mltb, bias, out0);
  k_edge<<<(E + 255) / 256, 256, 0, stream>>>(src, dst, et, sxw, dxw, rw,
                                              evals, esum, dcnt, hist);
  k_meta<<<1, 1024, 0, stream>>>(hist, cnt, poffs, repbase);
  k_dscan1<<<NBLK_D, 1024, 0, stream>>>(dcnt, dloc, dtot);
  k_dscan2<<<1, 128, 0, stream>>>(dtot, dboff);
  k_dscan3<<<NBLK_D, 1024, 0, stream>>>(dloc, dboff, doffs);
  k_scatter<<<(E + 255) / 256, 256, 0, stream>>>(src, dst, et, evals, esum, enorm,
                                                 repbase, cnt2rep, doffs, dcnt2,
                                                 gsrc, dposA, coef);
  int Vs = V / ns;
  for (int s = 0; s < ns; ++s) {
    int lo = s * Vs, hi = (s == ns - 1) ? V : (s + 1) * Vs;
    k_msg3<<<NGROUP * 2, 256, 0, stream>>>(xb, mbt, cnt, poffs, gsrc, dposA, coef,
                                           doffs, lo, hi, msgb);
    k_sum<<<(Vs + 3) / 4, 256, 0, stream>>>(msgb, doffs, dcnt, out0, lo, hi);
  }
  k_bn_stats<<<512, 256, 0, stream>>>(out0, colsum, colsumsq);
  k_bn_norm<<<(V * D + 255) / 256, 256, 0, stream>>>(out0, colsum, colsumsq);
}

// Round 7
// 502.022 us; speedup vs baseline: 1.3138x; 1.3138x over previous
//
#include <hip/hip_runtime.h>

#define V 80000
#define E 640000
#define D 128
#define NREL 500
#define HALF (E/2)
#define NGROUP 1000
#define EP (E + NGROUP * 32)
#define NBLK_D ((V + 1023) / 1024)
#define NREP 160
#define SLAB 4000   // E / NREP

typedef __attribute__((ext_vector_type(8))) short s8v;
typedef __attribute__((ext_vector_type(4))) float f4v;
typedef __attribute__((ext_vector_type(4))) int i4v;

__device__ __forceinline__ unsigned short f2bf(float f) {
  unsigned u = __float_as_uint(f);
  return (unsigned short)((u + 0x7fffu + ((u >> 16) & 1u)) >> 16);
}

__global__ void k_init(float* esum, float* colsum, float* colsumsq,
                       int* dcnt, int* dcnt2, int* hist, int* cnt2rep,
                       float* coef, int* gsrc, int* dposA) {
  int i = blockIdx.x * 256 + threadIdx.x;
  if (i < V) { esum[i] = 0.f; dcnt[i] = 0; dcnt2[i] = 0; }
  if (i < D) { colsum[i] = 0.f; colsumsq[i] = 0.f; }
  if (i < NGROUP * NREP) { hist[i] = 0; cnt2rep[i] = 0; }
  if (i < EP) { coef[i] = 0.f; gsrc[i] = 0; dposA[i] = -1; }
}

// fused prep: blocks [0,500)=rel/out1/rw/relb ; [500,628)=mltb ; [628,884)=wtb
__global__ void k_prep(const float* __restrict__ rel, const float* __restrict__ w_rel,
                       const float* __restrict__ attn_w, const float* __restrict__ loop_rel,
                       const float* __restrict__ loop_w, const float* __restrict__ in_w,
                       const float* __restrict__ out_w, float* __restrict__ out1,
                       float* __restrict__ rw, unsigned short* __restrict__ relb,
                       unsigned short* __restrict__ mltb, unsigned short* __restrict__ wtb) {
  int b = blockIdx.x, n = threadIdx.x;
  if (b < NREL) {
    __shared__ float rs[D];
    __shared__ float red[D];
    float rv = rel[b * D + n];
    rs[n] = rv;
    relb[b * D + n] = f2bf(rv);
    red[n] = rv * attn_w[D + n];
    __syncthreads();
    float acc = 0.f;
    #pragma unroll 8
    for (int j = 0; j < D; ++j) acc += rs[j] * w_rel[j * D + n];
    out1[b * D + n] = acc;
    if (n == 0) {
      float s = 0.f;
      for (int j = 0; j < D; ++j) s += red[j];
      rw[b] = s;
    }
  } else if (b < NREL + D) {
    int j = b - NREL;
    __shared__ float ls[2 * D];
    ls[n] = loop_rel[n]; ls[n + D] = loop_rel[n];
    __syncthreads();
    float acc = 0.f;
    #pragma unroll 8
    for (int k = 0; k < D; ++k) acc += ls[j + k] * loop_w[k * D + n];
    mltb[n * D + j] = f2bf(acc);
  } else {
    int bw = b - NREL - D;
    int h = bw >> 7, n2 = bw & 127;
    const float* W = h ? out_w : in_w;
    wtb[h * 16384 + n2 * D + n] = f2bf(W[n * D + n2]);
  }
}

// fused: x -> bf16 xb ; sxw/dxw projections (reads x once)
__global__ void k_xbproj(const float* __restrict__ x, const float* __restrict__ attn_w,
                         unsigned* __restrict__ xb32, float* __restrict__ sxw,
                         float* __restrict__ dxw) {
  int tid = threadIdx.x;
  int wid = tid >> 6, lane = tid & 63;
  float ws0 = attn_w[2 * lane], ws1 = attn_w[2 * lane + 1];
  float wd0 = attn_w[256 + 2 * lane], wd1 = attn_w[256 + 2 * lane + 1];
  for (int v = blockIdx.x * 4 + wid; v < V; v += 2048 * 4) {
    float2 xv = *(const float2*)&x[(size_t)v * D + 2 * lane];
    float ps = xv.x * ws0 + xv.y * ws1;
    float pd = xv.x * wd0 + xv.y * wd1;
    #pragma unroll
    for (int off = 32; off; off >>= 1) { ps += __shfl_xor(ps, off); pd += __shfl_xor(pd, off); }
    if (lane == 0) { sxw[v] = ps; dxw[v] = pd; }
    xb32[(size_t)v * 64 + lane] = (unsigned)f2bf(xv.x) | ((unsigned)f2bf(xv.y) << 16);
  }
}

// MbT[g][n][j] = sum_k rel_t[(j+k)%128] * W_h[k][n]  via MFMA
__global__ __launch_bounds__(256) void k_mbt2(const unsigned short* __restrict__ relb,
    const unsigned short* __restrict__ wtb, unsigned short* __restrict__ mbt) {
  __shared__ unsigned short relp[256];
  __shared__ unsigned short Wl[D * D];
  int g = blockIdx.x, tid = threadIdx.x;
  int t = (g >= NREL) ? g - NREL : g;
  const unsigned short* wt = wtb + (g >= NREL ? 16384 : 0);
  relp[tid] = relb[t * D + (tid & 127)];
  #pragma unroll
  for (int i = 0; i < 8; ++i) {
    int idx = tid + i * 256;
    int n = idx >> 4, kc = idx & 15;
    *(uint4*)((char*)Wl + n * 256 + ((kc ^ (n & 7)) << 4)) = *(const uint4*)(wt + n * D + kc * 8);
  }
  __syncthreads();
  int wid = tid >> 6, ln = tid & 15, hi = (tid & 63) >> 4;
  s8v af[2][4];
  #pragma unroll
  for (int m = 0; m < 2; ++m) {
    int j = wid * 32 + m * 16 + ln;
    #pragma unroll
    for (int ks = 0; ks < 4; ++ks) {
      int o = j + ks * 32 + hi * 8;
      s8v a;
      #pragma unroll
      for (int i = 0; i < 8; ++i) a[i] = (short)relp[o + i];
      af[m][ks] = a;
    }
  }
  f4v acc[2][8];
  #pragma unroll
  for (int m = 0; m < 2; ++m)
    #pragma unroll
    for (int nn = 0; nn < 8; ++nn) acc[m][nn] = (f4v){0.f, 0.f, 0.f, 0.f};
  #pragma unroll
  for (int ks = 0; ks < 4; ++ks) {
    #pragma unroll
    for (int nn = 0; nn < 8; ++nn) {
      int n2 = nn * 16 + ln;
      int kc = (ks * 4 + hi) ^ (n2 & 7);
      s8v b = *(const s8v*)((const char*)Wl + n2 * 256 + (kc << 4));
      #pragma unroll
      for (int m = 0; m < 2; ++m)
        acc[m][nn] = __builtin_amdgcn_mfma_f32_16x16x32_bf16(af[m][ks], b, acc[m][nn], 0, 0, 0);
    }
  }
  size_t gb = (size_t)g * (D * D);
  #pragma unroll
  for (int m = 0; m < 2; ++m)
    #pragma unroll
    for (int nn = 0; nn < 8; ++nn) {
      int jb = wid * 32 + m * 16 + hi * 4;
      unsigned long long pk = (unsigned long long)f2bf(acc[m][nn][0])
        | ((unsigned long long)f2bf(acc[m][nn][1]) << 16)
        | ((unsigned long long)f2bf(acc[m][nn][2]) << 32)
        | ((unsigned long long)f2bf(acc[m][nn][3]) << 48);
      *(unsigned long long*)&mbt[gb + (size_t)(nn * 16 + ln) * D + jb] = pk;
    }
}

// out0 init = (xb @ MloopT^T)/3 + bias  via MFMA
__global__ __launch_bounds__(256) void k_lgemm(const unsigned short* __restrict__ xb,
    const unsigned short* __restrict__ mltb, const float* __restrict__ bias,
    float* __restrict__ out0) {
  __shared__ unsigned short Wl[D * D];
  int tid = threadIdx.x;
  #pragma unroll
  for (int i = 0; i < 8; ++i) {
    int idx = tid + i * 256;
    int n = idx >> 4, kc = idx & 15;
    *(uint4*)((char*)Wl + n * 256 + ((kc ^ (n & 7)) << 4)) = *(const uint4*)(mltb + n * D + kc * 8);
  }
  __syncthreads();
  int wid = tid >> 6, ln = tid & 15, hi = (tid & 63) >> 4;
  int rbase = blockIdx.x * 128 + wid * 32;
  s8v af[2][4];
  #pragma unroll
  for (int m = 0; m < 2; ++m)
    #pragma unroll
    for (int ks = 0; ks < 4; ++ks)
      af[m][ks] = *(const s8v*)(xb + (size_t)(rbase + m * 16 + ln) * D + ks * 32 + hi * 8);
  f4v acc[2][8];
  #pragma unroll
  for (int m = 0; m < 2; ++m)
    #pragma unroll
    for (int nn = 0; nn < 8; ++nn) acc[m][nn] = (f4v){0.f, 0.f, 0.f, 0.f};
  #pragma unroll
  for (int ks = 0; ks < 4; ++ks) {
    #pragma unroll
    for (int nn = 0; nn < 8; ++nn) {
      int n2 = nn * 16 + ln;
      int kc = (ks * 4 + hi) ^ (n2 & 7);
      s8v b = *(const s8v*)((const char*)Wl + n2 * 256 + (kc << 4));
      #pragma unroll
      for (int m = 0; m < 2; ++m)
        acc[m][nn] = __builtin_amdgcn_mfma_f32_16x16x32_bf16(af[m][ks], b, acc[m][nn], 0, 0, 0);
    }
  }
  float bcol[8];
  #pragma unroll
  for (int nn = 0; nn < 8; ++nn) bcol[nn] = bias[nn * 16 + ln];
  #pragma unroll
  for (int m = 0; m < 2; ++m)
    #pragma unroll
    for (int nn = 0; nn < 8; ++nn)
      #pragma unroll
      for (int r = 0; r < 4; ++r)
        out0[(size_t)(rbase + m * 16 + hi * 4 + r) * D + nn * 16 + ln] =
            acc[m][nn][r] * (1.f / 3.f) + bcol[nn];
}

// fused per-edge phase A
__global__ void k_edge(const int* __restrict__ src, const int* __restrict__ dst,
                       const int* __restrict__ et, const float* __restrict__ sxw,
                       const float* __restrict__ dxw, const float* __restrict__ rw,
                       float* __restrict__ evals, float* __restrict__ esum,
                       int* __restrict__ dcnt, int* __restrict__ hist) {
  int i = blockIdx.x * 256 + threadIdx.x;
  if (i >= E) return;
  int d = dst[i];
  float ev = sxw[src[i]] + rw[et[i]] + dxw[d];
  ev = ev >= 0.f ? ev : 0.01f * ev;
  float xv = __expf(ev);
  evals[i] = xv;
  atomicAdd(&esum[d], xv);
  atomicAdd(&dcnt[d], 1);
  int g = et[i] + ((i >= HALF) ? NREL : 0);
  int r = i / SLAB;
  atomicAdd(&hist[g * NREP + r], 1);
}

// fused: cnt <- rowsum(hist); padded exclusive scan -> poffs; repbase
__global__ void k_meta(const int* __restrict__ hist, int* __restrict__ cnt,
                       int* __restrict__ poffs, int* __restrict__ repbase) {
  __shared__ int tmp[1024];
  int t = threadIdx.x;
  int c = 0;
  if (t < NGROUP) {
    for (int r = 0; r < NREP; ++r) c += hist[t * NREP + r];
    cnt[t] = c;
  }
  int pc = (c + 31) & ~31;
  tmp[t] = pc;
  __syncthreads();
  #pragma unroll
  for (int off = 1; off < 1024; off <<= 1) {
    int v = (t >= off) ? tmp[t - off] : 0;
    __syncthreads();
    tmp[t] += v;
    __syncthreads();
  }
  int po = tmp[t] - pc;
  poffs[t] = po;
  if (t < NGROUP) {
    int running = po;
    for (int r = 0; r < NREP; ++r) {
      repbase[t * NREP + r] = running;
      running += hist[t * NREP + r];
    }
  }
}

__global__ void k_dscan1(const int* __restrict__ dcnt, int* __restrict__ dloc,
                         int* __restrict__ dtot) {
  __shared__ int tmp[1024];
  int t = threadIdx.x, i = blockIdx.x * 1024 + t;
  int v = (i < V) ? dcnt[i] : 0;
  tmp[t] = v;
  __syncthreads();
  #pragma unroll
  for (int off = 1; off < 1024; off <<= 1) {
    int u = (t >= off) ? tmp[t - off] : 0;
    __syncthreads();
    tmp[t] += u;
    __syncthreads();
  }
  if (i < V) dloc[i] = tmp[t] - v;
  if (t == 1023) dtot[blockIdx.x] = tmp[t];
}

__global__ void k_dscan2(const int* __restrict__ dtot, int* __restrict__ dboff) {
  __shared__ int tmp[128];
  int t = threadIdx.x;
  int v = (t < NBLK_D) ? dtot[t] : 0;
  tmp[t] = v;
  __syncthreads();
  #pragma unroll
  for (int off = 1; off < 128; off <<= 1) {
    int u = (t >= off) ? tmp[t - off] : 0;
    __syncthreads();
    tmp[t] += u;
    __syncthreads();
  }
  dboff[t] = tmp[t] - v;
}

__global__ void k_dscan3(const int* __restrict__ dloc, const int* __restrict__ dboff,
                         int* __restrict__ doffs) {
  int i = blockIdx.x * 1024 + threadIdx.x;
  if (i < V) doffs[i] = dloc[i] + dboff[i >> 10];
}

__global__ void k_scatter(const int* __restrict__ src, const int* __restrict__ dst,
                          const int* __restrict__ et, const float* __restrict__ ee,
                          const float* __restrict__ esum, const float* __restrict__ enorm,
                          const int* __restrict__ repbase, int* __restrict__ cnt2rep,
                          const int* __restrict__ doffs, int* __restrict__ dcnt2,
                          int* __restrict__ gsrc, int* __restrict__ dposA,
                          float* __restrict__ coef) {
  int i = blockIdx.x * 256 + threadIdx.x;
  if (i >= E) return;
  int g = et[i] + ((i >= HALF) ? NREL : 0);
  int r = i / SLAB;
  int pos = repbase[g * NREP + r] + atomicAdd(&cnt2rep[g * NREP + r], 1);
  int d = dst[i];
  gsrc[pos] = src[i];
  coef[pos] = ee[i] / esum[d] * enorm[i] * (1.f / 3.f);
  int dr = atomicAdd(&dcnt2[d], 1);
  dposA[pos] = doffs[d] + dr;
}

// grouped gather-GEMM, 16-edge tiles, double-buffered A gather (no reg clamp)
__global__ __launch_bounds__(256) void k_msg3(const unsigned short* __restrict__ xb,
    const unsigned short* __restrict__ mbt, const int* __restrict__ cnt,
    const int* __restrict__ poffs, const int* __restrict__ gsrc,
    const int* __restrict__ dposA, const float* __restrict__ coef,
    const int* __restrict__ doffs, int loNode, int hiNode,
    unsigned short* __restrict__ msgb) {
  __shared__ uint4 Blds4[(D * 272) / 16];
  unsigned char* Bldsb = (unsigned char*)Blds4;
  int g = blockIdx.x;
  int c = cnt[g];
  if (c == 0) return;
  int tid = threadIdx.x;
  const uint4* Mg = (const uint4*)(mbt + (size_t)g * (D * D));
  #pragma unroll
  for (int i = 0; i < 8; ++i) {
    int idx = tid + i * 256;
    int row = idx >> 4, col = (idx & 15) * 16;
    Blds4[(row * 272 + col) >> 4] = Mg[idx];
  }
  __syncthreads();
  int b1 = doffs[loNode];
  int b2 = (hiNode >= V) ? E : doffs[hiNode];
  int wid = tid >> 6, ln = tid & 15, hi = (tid & 63) >> 4;
  int base0 = poffs[g];
  int nch = (c + 15) >> 4;
  int ch = wid;
  int sr = (ch < nch) ? gsrc[base0 + ch * 16 + ln] : 0;
  s8v afp[4];
  if (ch < nch) {
    const unsigned short* xr = xb + (size_t)sr * D + hi * 8;
    #pragma unroll
    for (int ks = 0; ks < 4; ++ks) afp[ks] = *(const s8v*)(xr + ks * 32);
  }
  for (; ch < nch; ch += 4) {
    int base = base0 + ch * 16;
    f4v cf = *(const f4v*)&coef[base + hi * 4];
    i4v dp = *(const i4v*)&dposA[base + hi * 4];
    int nc2 = ch + 4;
    int srn = (nc2 < nch) ? gsrc[base0 + nc2 * 16 + ln] : sr;
    s8v afc[4];
    #pragma unroll
    for (int ks = 0; ks < 4; ++ks) afc[ks] = afp[ks];
    f4v acc[8];
    #pragma unroll
    for (int n = 0; n < 8; ++n) acc[n] = (f4v){0.f, 0.f, 0.f, 0.f};
    #pragma unroll
    for (int ks = 0; ks < 4; ++ks) {
      #pragma unroll
      for (int n = 0; n < 8; ++n) {
        int row = n * 16 + ln;
        s8v bf = *(const s8v*)(Bldsb + row * 272 + ks * 64 + hi * 16);
        acc[n] = __builtin_amdgcn_mfma_f32_16x16x32_bf16(afc[ks], bf, acc[n], 0, 0, 0);
      }
    }
    // prefetch next chunk's A rows while softmax runs
    {
      const unsigned short* xr = xb + (size_t)srn * D + hi * 8;
      #pragma unroll
      for (int ks = 0; ks < 4; ++ks) afp[ks] = *(const s8v*)(xr + ks * 32);
    }
    sr = srn;
    f4v mx = acc[0];
    #pragma unroll
    for (int n = 1; n < 8; ++n)
      #pragma unroll
      for (int j = 0; j < 4; ++j) mx[j] = fmaxf(mx[j], acc[n][j]);
    #pragma unroll
    for (int off = 1; off < 16; off <<= 1)
      #pragma unroll
      for (int j = 0; j < 4; ++j) mx[j] = fmaxf(mx[j], __shfl_xor(mx[j], off));
    f4v sum = (f4v){0.f, 0.f, 0.f, 0.f};
    #pragma unroll
    for (int n = 0; n < 8; ++n)
      #pragma unroll
      for (int j = 0; j < 4; ++j) {
        float e = __expf(acc[n][j] - mx[j]);
        acc[n][j] = e;
        sum[j] += e;
      }
    #pragma unroll
    for (int off = 1; off < 16; off <<= 1)
      #pragma unroll
      for (int j = 0; j < 4; ++j) sum[j] += __shfl_xor(sum[j], off);
    #pragma unroll
    for (int j = 0; j < 4; ++j) {
      int dpos = dp[j];
      if (dpos >= b1 && dpos < b2) {
        size_t rowb = (size_t)(dpos - b1) * D;
        float s = cf[j] / sum[j];
        #pragma unroll
        for (int n = 0; n < 8; ++n)
          msgb[rowb + n * 16 + ln] = f2bf(acc[n][j] * s);
      }
    }
  }
}

// per-node segment sum of dst-sorted messages into out0
__global__ void k_sum(const unsigned short* __restrict__ msgb, const int* __restrict__ doffs,
                      const int* __restrict__ dcnt, float* __restrict__ out0,
                      int loNode, int hiNode) {
  int d = loNode + blockIdx.x * 4 + (threadIdx.x >> 6);
  if (d >= hiNode) return;
  int lane = threadIdx.x & 63;
  int b1 = doffs[loNode];
  int start = doffs[d] - b1, len = dcnt[d];
  float a0 = 0.f, a1 = 0.f;
  const unsigned short* mp = msgb + (size_t)start * D + lane * 2;
  for (int r = 0; r < len; ++r) {
    unsigned u = *(const unsigned*)(mp + (size_t)r * D);
    a0 += __uint_as_float(u << 16);
    a1 += __uint_as_float(u & 0xffff0000u);
  }
  float2* o = (float2*)&out0[(size_t)d * D + lane * 2];
  float2 v = *o;
  v.x += a0; v.y += a1;
  *o = v;
}

__global__ void k_bn_stats(const float* __restrict__ out0, float* __restrict__ colsum,
                           float* __restrict__ colsumsq) {
  int tid = threadIdx.x;
  int col = tid & 127;
  int v0 = blockIdx.x * 2 + (tid >> 7);
  float s = 0.f, s2 = 0.f;
  for (int v = v0; v < V; v += 1024) {
    float val = out0[(size_t)v * D + col];
    s += val; s2 += val * val;
  }
  atomicAdd(&colsum[col], s);
  atomicAdd(&colsumsq[col], s2);
}

__global__ void k_bn_norm(float* __restrict__ out0, const float* __restrict__ colsum,
                          const float* __restrict__ colsumsq) {
  int i = blockIdx.x * 256 + threadIdx.x;
  if (i >= V * D) return;
  int c = i & 127;
  float mean = colsum[c] * (1.f / V);
  float var = colsumsq[c] * (1.f / V) - mean * mean;
  out0[i] = (out0[i] - mean) * rsqrtf(var + 1e-5f);
}

extern "C" void kernel_launch(void* const* d_in, const int* in_sizes, int n_in,
                              void* d_out, int out_size, void* d_ws, size_t ws_size,
                              hipStream_t stream) {
  const float* x        = (const float*)d_in[0];
  const float* rel      = (const float*)d_in[4];
  const float* enorm    = (const float*)d_in[5];
  const float* in_w     = (const float*)d_in[6];
  const float* out_w    = (const float*)d_in[7];
  const float* loop_w   = (const float*)d_in[8];
  const float* w_rel    = (const float*)d_in[9];
  const float* loop_rel = (const float*)d_in[10];
  const float* attn_w   = (const float*)d_in[11];
  const float* bias     = (const float*)d_in[12];
  const int* src = (const int*)d_in[13];
  const int* dst = (const int*)d_in[14];
  const int* et  = (const int*)d_in[15];

  float* out0 = (float*)d_out;
  float* out1 = out0 + (size_t)V * D;

  float* base = (float*)d_ws;
  size_t off = 0;
  float* sxw = base + off;      off += V;
  float* dxw = base + off;      off += V;
  float* esum = base + off;     off += V;
  float* evals = base + off;    off += E;
  float* rw = base + off;       off += 512;
  float* colsum = base + off;   off += 128;
  float* colsumsq = base + off; off += 128;
  int* cnt = (int*)(base + off);   off += 1024;
  int* poffs = (int*)(base + off); off += 1024;
  int* hist = (int*)(base + off);     off += NGROUP * NREP;
  int* repbase = (int*)(base + off);  off += NGROUP * NREP;
  int* cnt2rep = (int*)(base + off);  off += NGROUP * NREP;
  int* dcnt = (int*)(base + off);  off += V;
  int* dcnt2 = (int*)(base + off); off += V;
  int* dloc = (int*)(base + off);  off += V;
  int* doffs = (int*)(base + off); off += V;
  int* dtot = (int*)(base + off);  off += 128;
  int* dboff = (int*)(base + off); off += 128;
  float* coef = base + off;        off += EP;
  int* gsrc = (int*)(base + off);  off += EP;
  int* dposA = (int*)(base + off); off += EP;
  unsigned short* mltb = (unsigned short*)(base + off); off += D * D / 2;
  unsigned short* relb = (unsigned short*)(base + off); off += NREL * D / 2;
  unsigned short* wtb  = (unsigned short*)(base + off); off += 2 * D * D / 2;
  unsigned short* xb   = (unsigned short*)(base + off); off += (size_t)V * D / 2;
  unsigned short* mbt  = (unsigned short*)(base + off); off += (size_t)NGROUP * D * D / 2;
  unsigned short* msgb = (unsigned short*)(base + off);

  size_t availF = (ws_size / 4 > off) ? (ws_size / 4 - off) : 0;
  int ns = 1;
  if ((size_t)EP * (D / 2) > availF) {
    ns = 2;
    while (ns < 64 && (size_t)(E / ns + 16384) * (D / 2) > availF) ns *= 2;
  }

  k_init<<<(EP + 255) / 256, 256, 0, stream>>>(esum, colsum, colsumsq, dcnt, dcnt2,
                                               hist, cnt2rep, coef, gsrc, dposA);
  k_prep<<<NREL + D + 256, 128, 0, stream>>>(rel, w_rel, attn_w, loop_rel, loop_w,
                                             in_w, out_w, out1, rw, relb, mltb, wtb);
  k_xbproj<<<2048, 256, 0, stream>>>(x, attn_w, (unsigned*)xb, sxw, dxw);
  k_mbt2<<<NGROUP, 256, 0, stream>>>(relb, wtb, mbt);
  k_lgemm<<<V / 128, 256, 0, stream>>>(xb, mltb, bias, out0);
  k_edge<<<(E + 255) / 256, 256, 0, stream>>>(src, dst, et, sxw, dxw, rw,
                                              evals, esum, dcnt, hist);
  k_meta<<<1, 1024, 0, stream>>>(hist, cnt, poffs, repbase);
  k_dscan1<<<NBLK_D, 1024, 0, stream>>>(dcnt, dloc, dtot);
  k_dscan2<<<1, 128, 0, stream>>>(dtot, dboff);
  k_dscan3<<<NBLK_D, 1024, 0, stream>>>(dloc, dboff, doffs);
  k_scatter<<<(E + 255) / 256, 256, 0, stream>>>(src, dst, et, evals, esum, enorm,
                                                 repbase, cnt2rep, doffs, dcnt2,
                                                 gsrc, dposA, coef);
  int Vs = V / ns;
  for (int s = 0; s < ns; ++s) {
    int lo = s * Vs, hi = (s == ns - 1) ? V : (s + 1) * Vs;
    k_msg3<<<NGROUP, 256, 0, stream>>>(xb, mbt, cnt, poffs, gsrc, dposA, coef,
                                       doffs, lo, hi, msgb);
    k_sum<<<(Vs + 3) / 4, 256, 0, stream>>>(msgb, doffs, dcnt, out0, lo, hi);
  }
  k_bn_stats<<<512, 256, 0, stream>>>(out0, colsum, colsumsq);
  k_bn_norm<<<(V * D + 255) / 256, 256, 0, stream>>>(out0, colsum, colsumsq);
}

// Round 8
// 449.887 us; speedup vs baseline: 1.4661x; 1.1159x over previous
//
#include <hip/hip_runtime.h>

#define V 80000
#define E 640000
#define D 128
#define NREL 500
#define HALF (E/2)
#define NGROUP 1000
#define EP (E + NGROUP * 32)
#define NBLK_D ((V + 1023) / 1024)
#define NREP 160
#define SLAB 4000   // E / NREP

typedef __attribute__((ext_vector_type(8))) short s8v;
typedef __attribute__((ext_vector_type(4))) float f4v;
typedef __attribute__((ext_vector_type(4))) int i4v;
typedef unsigned long long u64;

__device__ __forceinline__ unsigned short f2bf(float f) {
  unsigned u = __float_as_uint(f);
  return (unsigned short)((u + 0x7fffu + ((u >> 16) & 1u)) >> 16);
}

__global__ void k_init(u64* packed, float* colsum, float* colsumsq,
                       int* hist, int* gsrc, int* dposA) {
  int i = blockIdx.x * 256 + threadIdx.x;
  if (i < V) packed[i] = 0ull;
  if (i < D) { colsum[i] = 0.f; colsumsq[i] = 0.f; }
  if (i < NGROUP * NREP) hist[i] = 0;
  if (i < EP) { gsrc[i] = 0; dposA[i] = -1; }
}

// fused prep: blocks [0,500)=rel/out1/rw/relb ; [500,628)=mltb ; [628,884)=wtb
__global__ void k_prep(const float* __restrict__ rel, const float* __restrict__ w_rel,
                       const float* __restrict__ attn_w, const float* __restrict__ loop_rel,
                       const float* __restrict__ loop_w, const float* __restrict__ in_w,
                       const float* __restrict__ out_w, float* __restrict__ out1,
                       float* __restrict__ rw, unsigned short* __restrict__ relb,
                       unsigned short* __restrict__ mltb, unsigned short* __restrict__ wtb) {
  int b = blockIdx.x, n = threadIdx.x;
  if (b < NREL) {
    __shared__ float rs[D];
    __shared__ float red[D];
    float rv = rel[b * D + n];
    rs[n] = rv;
    relb[b * D + n] = f2bf(rv);
    red[n] = rv * attn_w[D + n];
    __syncthreads();
    float acc = 0.f;
    #pragma unroll 8
    for (int j = 0; j < D; ++j) acc += rs[j] * w_rel[j * D + n];
    out1[b * D + n] = acc;
    if (n == 0) {
      float s = 0.f;
      for (int j = 0; j < D; ++j) s += red[j];
      rw[b] = s;
    }
  } else if (b < NREL + D) {
    int j = b - NREL;
    __shared__ float ls[2 * D];
    ls[n] = loop_rel[n]; ls[n + D] = loop_rel[n];
    __syncthreads();
    float acc = 0.f;
    #pragma unroll 8
    for (int k = 0; k < D; ++k) acc += ls[j + k] * loop_w[k * D + n];
    mltb[n * D + j] = f2bf(acc);
  } else {
    int bw = b - NREL - D;
    int h = bw >> 7, n2 = bw & 127;
    const float* W = h ? out_w : in_w;
    wtb[h * 16384 + n2 * D + n] = f2bf(W[n * D + n2]);
  }
}

// fused: x -> bf16 xb ; sxw/dxw projections (reads x once)
__global__ void k_xbproj(const float* __restrict__ x, const float* __restrict__ attn_w,
                         unsigned* __restrict__ xb32, float* __restrict__ sxw,
                         float* __restrict__ dxw) {
  int tid = threadIdx.x;
  int wid = tid >> 6, lane = tid & 63;
  float ws0 = attn_w[2 * lane], ws1 = attn_w[2 * lane + 1];
  float wd0 = attn_w[256 + 2 * lane], wd1 = attn_w[256 + 2 * lane + 1];
  for (int v = blockIdx.x * 4 + wid; v < V; v += 2048 * 4) {
    float2 xv = *(const float2*)&x[(size_t)v * D + 2 * lane];
    float ps = xv.x * ws0 + xv.y * ws1;
    float pd = xv.x * wd0 + xv.y * wd1;
    #pragma unroll
    for (int off = 32; off; off >>= 1) { ps += __shfl_xor(ps, off); pd += __shfl_xor(pd, off); }
    if (lane == 0) { sxw[v] = ps; dxw[v] = pd; }
    xb32[(size_t)v * 64 + lane] = (unsigned)f2bf(xv.x) | ((unsigned)f2bf(xv.y) << 16);
  }
}

// MbT[g][n][j] = sum_k rel_t[(j+k)%128] * W_h[k][n]  via MFMA
__global__ __launch_bounds__(256) void k_mbt2(const unsigned short* __restrict__ relb,
    const unsigned short* __restrict__ wtb, unsigned short* __restrict__ mbt) {
  __shared__ unsigned short relp[256];
  __shared__ unsigned short Wl[D * D];
  int g = blockIdx.x, tid = threadIdx.x;
  int t = (g >= NREL) ? g - NREL : g;
  const unsigned short* wt = wtb + (g >= NREL ? 16384 : 0);
  relp[tid] = relb[t * D + (tid & 127)];
  #pragma unroll
  for (int i = 0; i < 8; ++i) {
    int idx = tid + i * 256;
    int n = idx >> 4, kc = idx & 15;
    *(uint4*)((char*)Wl + n * 256 + ((kc ^ (n & 7)) << 4)) = *(const uint4*)(wt + n * D + kc * 8);
  }
  __syncthreads();
  int wid = tid >> 6, ln = tid & 15, hi = (tid & 63) >> 4;
  s8v af[2][4];
  #pragma unroll
  for (int m = 0; m < 2; ++m) {
    int j = wid * 32 + m * 16 + ln;
    #pragma unroll
    for (int ks = 0; ks < 4; ++ks) {
      int o = j + ks * 32 + hi * 8;
      s8v a;
      #pragma unroll
      for (int i = 0; i < 8; ++i) a[i] = (short)relp[o + i];
      af[m][ks] = a;
    }
  }
  f4v acc[2][8];
  #pragma unroll
  for (int m = 0; m < 2; ++m)
    #pragma unroll
    for (int nn = 0; nn < 8; ++nn) acc[m][nn] = (f4v){0.f, 0.f, 0.f, 0.f};
  #pragma unroll
  for (int ks = 0; ks < 4; ++ks) {
    #pragma unroll
    for (int nn = 0; nn < 8; ++nn) {
      int n2 = nn * 16 + ln;
      int kc = (ks * 4 + hi) ^ (n2 & 7);
      s8v b = *(const s8v*)((const char*)Wl + n2 * 256 + (kc << 4));
      #pragma unroll
      for (int m = 0; m < 2; ++m)
        acc[m][nn] = __builtin_amdgcn_mfma_f32_16x16x32_bf16(af[m][ks], b, acc[m][nn], 0, 0, 0);
    }
  }
  size_t gb = (size_t)g * (D * D);
  #pragma unroll
  for (int m = 0; m < 2; ++m)
    #pragma unroll
    for (int nn = 0; nn < 8; ++nn) {
      int jb = wid * 32 + m * 16 + hi * 4;
      u64 pk = (u64)f2bf(acc[m][nn][0])
        | ((u64)f2bf(acc[m][nn][1]) << 16)
        | ((u64)f2bf(acc[m][nn][2]) << 32)
        | ((u64)f2bf(acc[m][nn][3]) << 48);
      *(u64*)&mbt[gb + (size_t)(nn * 16 + ln) * D + jb] = pk;
    }
}

// out0 init = (xb @ MloopT^T)/3 + bias  via MFMA
__global__ __launch_bounds__(256) void k_lgemm(const unsigned short* __restrict__ xb,
    const unsigned short* __restrict__ mltb, const float* __restrict__ bias,
    float* __restrict__ out0) {
  __shared__ unsigned short Wl[D * D];
  int tid = threadIdx.x;
  #pragma unroll
  for (int i = 0; i < 8; ++i) {
    int idx = tid + i * 256;
    int n = idx >> 4, kc = idx & 15;
    *(uint4*)((char*)Wl + n * 256 + ((kc ^ (n & 7)) << 4)) = *(const uint4*)(mltb + n * D + kc * 8);
  }
  __syncthreads();
  int wid = tid >> 6, ln = tid & 15, hi = (tid & 63) >> 4;
  int rbase = blockIdx.x * 128 + wid * 32;
  s8v af[2][4];
  #pragma unroll
  for (int m = 0; m < 2; ++m)
    #pragma unroll
    for (int ks = 0; ks < 4; ++ks)
      af[m][ks] = *(const s8v*)(xb + (size_t)(rbase + m * 16 + ln) * D + ks * 32 + hi * 8);
  f4v acc[2][8];
  #pragma unroll
  for (int m = 0; m < 2; ++m)
    #pragma unroll
    for (int nn = 0; nn < 8; ++nn) acc[m][nn] = (f4v){0.f, 0.f, 0.f, 0.f};
  #pragma unroll
  for (int ks = 0; ks < 4; ++ks) {
    #pragma unroll
    for (int nn = 0; nn < 8; ++nn) {
      int n2 = nn * 16 + ln;
      int kc = (ks * 4 + hi) ^ (n2 & 7);
      s8v b = *(const s8v*)((const char*)Wl + n2 * 256 + (kc << 4));
      #pragma unroll
      for (int m = 0; m < 2; ++m)
        acc[m][nn] = __builtin_amdgcn_mfma_f32_16x16x32_bf16(af[m][ks], b, acc[m][nn], 0, 0, 0);
    }
  }
  float bcol[8];
  #pragma unroll
  for (int nn = 0; nn < 8; ++nn) bcol[nn] = bias[nn * 16 + ln];
  #pragma unroll
  for (int m = 0; m < 2; ++m)
    #pragma unroll
    for (int nn = 0; nn < 8; ++nn)
      #pragma unroll
      for (int r = 0; r < 4; ++r)
        out0[(size_t)(rbase + m * 16 + hi * 4 + r) * D + nn * 16 + ln] =
            acc[m][nn][r] * (1.f / 3.f) + bcol[nn];
}

// per-edge phase A: one packed u64 atomic returns dst-rank AND accumulates
// esum (fixed point 2^-16, exact integer adds) + count; hist atomic returns grank
__global__ void k_edge(const int* __restrict__ src, const int* __restrict__ dst,
                       const int* __restrict__ et, const float* __restrict__ sxw,
                       const float* __restrict__ dxw, const float* __restrict__ rw,
                       float* __restrict__ evals, u64* __restrict__ packed,
                       int* __restrict__ hist, unsigned short* __restrict__ drank,
                       unsigned short* __restrict__ grank) {
  int i = blockIdx.x * 256 + threadIdx.x;
  if (i >= E) return;
  int d = dst[i];
  float ev = sxw[src[i]] + rw[et[i]] + dxw[d];
  ev = ev >= 0.f ? ev : 0.01f * ev;
  float xv = __expf(ev);
  evals[i] = xv;
  u64 inc = (1ull << 48) + (u64)(xv * 65536.f + 0.5f);
  u64 old = atomicAdd(&packed[d], inc);
  drank[i] = (unsigned short)(old >> 48);
  int g = et[i] + ((i >= HALF) ? NREL : 0);
  int r = i / SLAB;
  int gr = atomicAdd(&hist[g * NREP + r], 1);
  grank[i] = (unsigned short)gr;
}

// fused: cnt <- rowsum(hist); padded exclusive scan -> poffs; repbase
__global__ void k_meta(const int* __restrict__ hist, int* __restrict__ cnt,
                       int* __restrict__ poffs, int* __restrict__ repbase) {
  __shared__ int tmp[1024];
  int t = threadIdx.x;
  int c = 0;
  if (t < NGROUP) {
    for (int r = 0; r < NREP; ++r) c += hist[t * NREP + r];
    cnt[t] = c;
  }
  int pc = (c + 31) & ~31;
  tmp[t] = pc;
  __syncthreads();
  #pragma unroll
  for (int off = 1; off < 1024; off <<= 1) {
    int v = (t >= off) ? tmp[t - off] : 0;
    __syncthreads();
    tmp[t] += v;
    __syncthreads();
  }
  int po = tmp[t] - pc;
  poffs[t] = po;
  if (t < NGROUP) {
    int running = po;
    for (int r = 0; r < NREP; ++r) {
      repbase[t * NREP + r] = running;
      running += hist[t * NREP + r];
    }
  }
}

// decode packed -> esum + count; block scan of counts
__global__ void k_dscan1(const u64* __restrict__ packed, float* __restrict__ esum,
                         int* __restrict__ dloc, int* __restrict__ dtot) {
  __shared__ int tmp[1024];
  int t = threadIdx.x, i = blockIdx.x * 1024 + t;
  int v = 0;
  if (i < V) {
    u64 q = packed[i];
    esum[i] = (float)(q & 0xFFFFFFFFFFFFull) * (1.f / 65536.f);
    v = (int)(q >> 48);
  }
  tmp[t] = v;
  __syncthreads();
  #pragma unroll
  for (int off = 1; off < 1024; off <<= 1) {
    int u = (t >= off) ? tmp[t - off] : 0;
    __syncthreads();
    tmp[t] += u;
    __syncthreads();
  }
  if (i < V) dloc[i] = tmp[t] - v;
  if (t == 1023) dtot[blockIdx.x] = tmp[t];
}

__global__ void k_dscan2(const int* __restrict__ dtot, int* __restrict__ dboff) {
  __shared__ int tmp[128];
  int t = threadIdx.x;
  int v = (t < NBLK_D) ? dtot[t] : 0;
  tmp[t] = v;
  __syncthreads();
  #pragma unroll
  for (int off = 1; off < 128; off <<= 1) {
    int u = (t >= off) ? tmp[t - off] : 0;
    __syncthreads();
    tmp[t] += u;
    __syncthreads();
  }
  dboff[t] = tmp[t] - v;
}

__global__ void k_dscan3(const int* __restrict__ dloc, const int* __restrict__ dboff,
                         int* __restrict__ doffs) {
  int i = blockIdx.x * 1024 + threadIdx.x;
  if (i < V) doffs[i] = dloc[i] + dboff[i >> 10];
  if (i == 0) doffs[V] = E;
}

// atomic-free scatter: positions fully determined by repbase/grank, doffs/drank
__global__ void k_scatter(const int* __restrict__ src, const int* __restrict__ dst,
                          const int* __restrict__ et, const float* __restrict__ ee,
                          const float* __restrict__ esum, const float* __restrict__ enorm,
                          const int* __restrict__ repbase, const int* __restrict__ doffs,
                          const unsigned short* __restrict__ drank,
                          const unsigned short* __restrict__ grank,
                          int* __restrict__ gsrc, int* __restrict__ dposA,
                          float* __restrict__ coef) {
  int i = blockIdx.x * 256 + threadIdx.x;
  if (i >= E) return;
  int g = et[i] + ((i >= HALF) ? NREL : 0);
  int r = i / SLAB;
  int pos = repbase[g * NREP + r] + (int)grank[i];
  int d = dst[i];
  gsrc[pos] = src[i];
  coef[pos] = ee[i] / esum[d] * enorm[i] * (1.f / 3.f);
  dposA[pos] = doffs[d] + (int)drank[i];
}

// grouped gather-GEMM, 16-edge tiles, double-buffered A gather
__global__ __launch_bounds__(256) void k_msg3(const unsigned short* __restrict__ xb,
    const unsigned short* __restrict__ mbt, const int* __restrict__ cnt,
    const int* __restrict__ poffs, const int* __restrict__ gsrc,
    const int* __restrict__ dposA, const float* __restrict__ coef,
    const int* __restrict__ doffs, int loNode, int hiNode,
    unsigned short* __restrict__ msgb) {
  __shared__ uint4 Blds4[(D * 272) / 16];
  unsigned char* Bldsb = (unsigned char*)Blds4;
  int g = blockIdx.x;
  int c = cnt[g];
  if (c == 0) return;
  int tid = threadIdx.x;
  const uint4* Mg = (const uint4*)(mbt + (size_t)g * (D * D));
  #pragma unroll
  for (int i = 0; i < 8; ++i) {
    int idx = tid + i * 256;
    int row = idx >> 4, col = (idx & 15) * 16;
    Blds4[(row * 272 + col) >> 4] = Mg[idx];
  }
  __syncthreads();
  int b1 = doffs[loNode];
  int b2 = doffs[hiNode];
  int wid = tid >> 6, ln = tid & 15, hi = (tid & 63) >> 4;
  int base0 = poffs[g];
  int nch = (c + 15) >> 4;
  int ch = wid;
  int sr = (ch < nch) ? gsrc[base0 + ch * 16 + ln] : 0;
  s8v afp[4];
  if (ch < nch) {
    const unsigned short* xr = xb + (size_t)sr * D + hi * 8;
    #pragma unroll
    for (int ks = 0; ks < 4; ++ks) afp[ks] = *(const s8v*)(xr + ks * 32);
  }
  for (; ch < nch; ch += 4) {
    int base = base0 + ch * 16;
    f4v cf = *(const f4v*)&coef[base + hi * 4];
    i4v dp = *(const i4v*)&dposA[base + hi * 4];
    int nc2 = ch + 4;
    int srn = (nc2 < nch) ? gsrc[base0 + nc2 * 16 + ln] : sr;
    s8v afc[4];
    #pragma unroll
    for (int ks = 0; ks < 4; ++ks) afc[ks] = afp[ks];
    f4v acc[8];
    #pragma unroll
    for (int n = 0; n < 8; ++n) acc[n] = (f4v){0.f, 0.f, 0.f, 0.f};
    #pragma unroll
    for (int ks = 0; ks < 4; ++ks) {
      #pragma unroll
      for (int n = 0; n < 8; ++n) {
        int row = n * 16 + ln;
        s8v bf = *(const s8v*)(Bldsb + row * 272 + ks * 64 + hi * 16);
        acc[n] = __builtin_amdgcn_mfma_f32_16x16x32_bf16(afc[ks], bf, acc[n], 0, 0, 0);
      }
    }
    {
      const unsigned short* xr = xb + (size_t)srn * D + hi * 8;
      #pragma unroll
      for (int ks = 0; ks < 4; ++ks) afp[ks] = *(const s8v*)(xr + ks * 32);
    }
    sr = srn;
    f4v mx = acc[0];
    #pragma unroll
    for (int n = 1; n < 8; ++n)
      #pragma unroll
      for (int j = 0; j < 4; ++j) mx[j] = fmaxf(mx[j], acc[n][j]);
    #pragma unroll
    for (int off = 1; off < 16; off <<= 1)
      #pragma unroll
      for (int j = 0; j < 4; ++j) mx[j] = fmaxf(mx[j], __shfl_xor(mx[j], off));
    f4v sum = (f4v){0.f, 0.f, 0.f, 0.f};
    #pragma unroll
    for (int n = 0; n < 8; ++n)
      #pragma unroll
      for (int j = 0; j < 4; ++j) {
        float e = __expf(acc[n][j] - mx[j]);
        acc[n][j] = e;
        sum[j] += e;
      }
    #pragma unroll
    for (int off = 1; off < 16; off <<= 1)
      #pragma unroll
      for (int j = 0; j < 4; ++j) sum[j] += __shfl_xor(sum[j], off);
    #pragma unroll
    for (int j = 0; j < 4; ++j) {
      int dpos = dp[j];
      if (dpos >= b1 && dpos < b2) {
        size_t rowb = (size_t)(dpos - b1) * D;
        float s = cf[j] / sum[j];
        #pragma unroll
        for (int n = 0; n < 8; ++n)
          msgb[rowb + n * 16 + ln] = f2bf(acc[n][j] * s);
      }
    }
  }
}

// per-node segment sum of dst-sorted messages into out0 (len from doffs diff)
__global__ void k_sum(const unsigned short* __restrict__ msgb, const int* __restrict__ doffs,
                      float* __restrict__ out0, int loNode, int hiNode) {
  int d = loNode + blockIdx.x * 4 + (threadIdx.x >> 6);
  if (d >= hiNode) return;
  int lane = threadIdx.x & 63;
  int b1 = doffs[loNode];
  int s0 = doffs[d];
  int len = doffs[d + 1] - s0;
  int start = s0 - b1;
  float a0 = 0.f, a1 = 0.f;
  const unsigned short* mp = msgb + (size_t)start * D + lane * 2;
  for (int r = 0; r < len; ++r) {
    unsigned u = *(const unsigned*)(mp + (size_t)r * D);
    a0 += __uint_as_float(u << 16);
    a1 += __uint_as_float(u & 0xffff0000u);
  }
  float2* o = (float2*)&out0[(size_t)d * D + lane * 2];
  float2 v = *o;
  v.x += a0; v.y += a1;
  *o = v;
}

__global__ void k_bn_stats(const float* __restrict__ out0, float* __restrict__ colsum,
                           float* __restrict__ colsumsq) {
  int tid = threadIdx.x;
  int col = tid & 127;
  int v0 = blockIdx.x * 2 + (tid >> 7);
  float s = 0.f, s2 = 0.f;
  for (int v = v0; v < V; v += 1024) {
    float val = out0[(size_t)v * D + col];
    s += val; s2 += val * val;
  }
  atomicAdd(&colsum[col], s);
  atomicAdd(&colsumsq[col], s2);
}

__global__ void k_bn_norm(float* __restrict__ out0, const float* __restrict__ colsum,
                          const float* __restrict__ colsumsq) {
  int i = blockIdx.x * 256 + threadIdx.x;
  if (i >= V * D) return;
  int c = i & 127;
  float mean = colsum[c] * (1.f / V);
  float var = colsumsq[c] * (1.f / V) - mean * mean;
  out0[i] = (out0[i] - mean) * rsqrtf(var + 1e-5f);
}

extern "C" void kernel_launch(void* const* d_in, const int* in_sizes, int n_in,
                              void* d_out, int out_size, void* d_ws, size_t ws_size,
                              hipStream_t stream) {
  const float* x        = (const float*)d_in[0];
  const float* rel      = (const float*)d_in[4];
  const float* enorm    = (const float*)d_in[5];
  const float* in_w     = (const float*)d_in[6];
  const float* out_w    = (const float*)d_in[7];
  const float* loop_w   = (const float*)d_in[8];
  const float* w_rel    = (const float*)d_in[9];
  const float* loop_rel = (const float*)d_in[10];
  const float* attn_w   = (const float*)d_in[11];
  const float* bias     = (const float*)d_in[12];
  const int* src = (const int*)d_in[13];
  const int* dst = (const int*)d_in[14];
  const int* et  = (const int*)d_in[15];

  float* out0 = (float*)d_out;
  float* out1 = out0 + (size_t)V * D;

  float* base = (float*)d_ws;
  size_t off = 0;
  float* sxw = base + off;      off += V;
  float* dxw = base + off;      off += V;
  float* esum = base + off;     off += V;
  float* evals = base + off;    off += E;
  float* rw = base + off;       off += 512;
  float* colsum = base + off;   off += 128;
  float* colsumsq = base + off; off += 128;
  int* cnt = (int*)(base + off);   off += 1024;
  int* poffs = (int*)(base + off); off += 1024;
  int* hist = (int*)(base + off);     off += NGROUP * NREP;
  int* repbase = (int*)(base + off);  off += NGROUP * NREP;
  u64* packed = (u64*)(base + off);   off += 2 * V;   // even float offset -> 8B aligned
  int* dloc = (int*)(base + off);  off += V;
  int* doffs = (int*)(base + off); off += V + 2;
  int* dtot = (int*)(base + off);  off += 128;
  int* dboff = (int*)(base + off); off += 128;
  unsigned short* drank = (unsigned short*)(base + off); off += E / 2;
  unsigned short* grank = (unsigned short*)(base + off); off += E / 2;
  float* coef = base + off;        off += EP;
  int* gsrc = (int*)(base + off);  off += EP;
  int* dposA = (int*)(base + off); off += EP;
  unsigned short* mltb = (unsigned short*)(base + off); off += D * D / 2;
  unsigned short* relb = (unsigned short*)(base + off); off += NREL * D / 2;
  unsigned short* wtb  = (unsigned short*)(base + off); off += 2 * D * D / 2;
  unsigned short* xb   = (unsigned short*)(base + off); off += (size_t)V * D / 2;
  unsigned short* mbt  = (unsigned short*)(base + off); off += (size_t)NGROUP * D * D / 2;
  unsigned short* msgb = (unsigned short*)(base + off);

  size_t availF = (ws_size / 4 > off) ? (ws_size / 4 - off) : 0;
  int ns = 1;
  if ((size_t)EP * (D / 2) > availF) {
    ns = 2;
    while (ns < 64 && (size_t)(E / ns + 16384) * (D / 2) > availF) ns *= 2;
  }

  k_init<<<(EP + 255) / 256, 256, 0, stream>>>(packed, colsum, colsumsq, hist, gsrc, dposA);
  k_prep<<<NREL + D + 256, 128, 0, stream>>>(rel, w_rel, attn_w, loop_rel, loop_w,
                                             in_w, out_w, out1, rw, relb, mltb, wtb);
  k_xbproj<<<2048, 256, 0, stream>>>(x, attn_w, (unsigned*)xb, sxw, dxw);
  k_mbt2<<<NGROUP, 256, 0, stream>>>(relb, wtb, mbt);
  k_lgemm<<<V / 128, 256, 0, stream>>>(xb, mltb, bias, out0);
  k_edge<<<(E + 255) / 256, 256, 0, stream>>>(src, dst, et, sxw, dxw, rw,
                                              evals, packed, hist, drank, grank);
  k_meta<<<1, 1024, 0, stream>>>(hist, cnt, poffs, repbase);
  k_dscan1<<<NBLK_D, 1024, 0, stream>>>(packed, esum, dloc, dtot);
  k_dscan2<<<1, 128, 0, stream>>>(dtot, dboff);
  k_dscan3<<<NBLK_D, 1024, 0, stream>>>(dloc, dboff, doffs);
  k_scatter<<<(E + 255) / 256, 256, 0, stream>>>(src, dst, et, evals, esum, enorm,
                                                 repbase, doffs, drank, grank,
                                                 gsrc, dposA, coef);
  int Vs = V / ns;
  for (int s = 0; s < ns; ++s) {
    int lo = s * Vs, hi = (s == ns - 1) ? V : (s + 1) * Vs;
    k_msg3<<<NGROUP, 256, 0, stream>>>(xb, mbt, cnt, poffs, gsrc, dposA, coef,
                                       doffs, lo, hi, msgb);
    k_sum<<<(Vs + 3) / 4, 256, 0, stream>>>(msgb, doffs, out0, lo, hi);
  }
  k_bn_stats<<<512, 256, 0, stream>>>(out0, colsum, colsumsq);
  k_bn_norm<<<(V * D + 255) / 256, 256, 0, stream>>>(out0, colsum, colsumsq);
}